// Round 4
// baseline (228.834 us; speedup 1.0000x reference)
//
#include <hip/hip_runtime.h>
#include <hip/hip_bf16.h>
#include <math.h>

#define EMBED 768
#define NHEAD 12
#define HDIM 64
#define SEQ 2048
#define BATCH 4

typedef __hip_bfloat16 bf16;
typedef __attribute__((ext_vector_type(8))) short bf16x8;   // 8 bf16 / 4 VGPRs
typedef __attribute__((ext_vector_type(4))) short s16x4;
typedef __attribute__((ext_vector_type(4))) float f32x4;
typedef __attribute__((ext_vector_type(2))) unsigned int u32x2;

__device__ inline float b2f(bf16 v) { return __bfloat162float(v); }
__device__ inline bf16 f2b(float v) { return __float2bfloat16(v); }
__device__ inline unsigned pk2(float a, float b) {
  return (unsigned)__bfloat16_as_ushort(f2b(a)) |
         ((unsigned)__bfloat16_as_ushort(f2b(b)) << 16);
}

// async global->LDS, 16B per lane. LDS dest = wave-uniform base + lane*16.
__device__ inline void gl_lds16(const bf16* g, bf16* l) {
  __builtin_amdgcn_global_load_lds(
      (const __attribute__((address_space(1))) void*)g,
      (__attribute__((address_space(3))) void*)l, 16, 0, 0);
}

#define NX4  (BATCH * SEQ * EMBED / 4)
#define NWQ4 (3 * EMBED * EMBED / 4)
#define NWP4 (EMBED * EMBED / 4)

// ---------------------------------------------------------------------------
// One fused f32->bf16 convert for x, w_qkv, w_proj (segmented index space).
// ---------------------------------------------------------------------------
__global__ __launch_bounds__(256) void cvt_all(
    const float* __restrict__ x, const float* __restrict__ wq,
    const float* __restrict__ wp, bf16* __restrict__ xb,
    bf16* __restrict__ wqb, bf16* __restrict__ wpb) {
  int i = blockIdx.x * 256 + threadIdx.x;
  const float* src;
  bf16* dst;
  int k;
  if (i < NX4) {
    src = x; dst = xb; k = i;
  } else if (i < NX4 + NWQ4) {
    src = wq; dst = wqb; k = i - NX4;
  } else if (i < NX4 + NWQ4 + NWP4) {
    src = wp; dst = wpb; k = i - NX4 - NWQ4;
  } else {
    return;
  }
  float4 v = ((const float4*)src)[k];
  s16x4 o;
  o[0] = (short)__bfloat16_as_ushort(f2b(v.x));
  o[1] = (short)__bfloat16_as_ushort(f2b(v.y));
  o[2] = (short)__bfloat16_as_ushort(f2b(v.z));
  o[3] = (short)__bfloat16_as_ushort(f2b(v.w));
  *(s16x4*)(dst + 4 * (size_t)k) = o;
}

// ---------------------------------------------------------------------------
// MFMA GEMM, operand-swapped (computes C^T tiles).
// R16: depth-2 prefetch + counted vmcnt (T4). Per step t:
//   compute(t, buf t&1) -> raw s_barrier (B1: WAR, all reads of buf done)
//   -> STAGE(t+2 -> buf t&1) -> s_waitcnt vmcnt(8) (drains own t+1 loads,
//   which had a full compute phase in flight; t+2's 8 stay outstanding)
//   -> raw s_barrier (B2: every wave's t+1 loads landed).
//   Raw barriers carry NO implicit vmcnt(0) — loads span ~2 steps.
//   Race audit: B1 orders reads-before-overwrite; each wave drains its own
//   t+1 before B2, so after B2 all waves' t+1 data is resident.
// R16b: bijective XCD swizzle (nwg%8==0: 1152, 384): XCD k gets nwg/8
//   contiguous logical tiles = 8 m-rows x full n -> A panels (1.6MB) and
//   W (3.5MB) L2-resident per XCD.
// R14 (kept): BK=64, both-sides XOR swizzle — DMA source chunk
//   (lane&7)^(lane>>3), read slot (h*4+g)^(c&7); verified R2.
// MODE 0: scatter Q(x 0.125*log2e) -> [B,H,N,D], K -> [B,H,N,D],
//         V -> [B,H,D,N] (bf16)
// MODE 1: outF[m,o] f32 row-major
// ---------------------------------------------------------------------------
template <int MODE>
__global__ __launch_bounds__(256) void gemm_mfma(
    const bf16* __restrict__ A, const bf16* __restrict__ W,
    const float* __restrict__ bias, float* __restrict__ outF,
    bf16* __restrict__ outQ, bf16* __restrict__ outK, bf16* __restrict__ outV,
    int M, int N, int K) {
  __shared__ bf16 As[2][128][64];
  __shared__ bf16 Bs[2][128][64];
  const int t = threadIdx.x;
  const int w = t >> 6;
  const int lane = t & 63;
  const int g = lane >> 4, c = lane & 15;

  // XCD-aware remap of the flat block id (hardware dispatch order = x-fastest)
  const int bid = blockIdx.y * gridDim.x + blockIdx.x;
  const int nwg = gridDim.x * gridDim.y;      // 1152 / 384, both % 8 == 0
  const int cpx = nwg >> 3;
  const int swz = (bid & 7) * cpx + (bid >> 3);
  const int m0 = (swz / gridDim.x) * 128, n0 = (swz % gridDim.x) * 128;

  const int wr = (w >> 1) * 64;   // m-dim tile base (As)
  const int wc = (w & 1) * 64;    // o-dim tile base (Bs)

  // DMA mapping: 1KB per instr = 8 rows x 128B. Source chunk pre-swizzled.
  const int srow = lane >> 3;          // 0..7 row within 8-row stripe
  const int l8 = lane & 7;             // LDS 16B-slot within row
  const int sseg = (l8 ^ srow) * 8;    // swizzled global chunk (bf16 elems)

  f32x4 acc[4][4] = {};   // acc[i][j]: i over o-tiles (W), j over m-tiles (x)

  const int nsteps = K >> 6;           // K=768 -> 12

  // prologue: stage step 0 into buf 0 (full drain), then step 1 into buf 1
#pragma unroll
  for (int i = 0; i < 4; i++) {
    int r = w * 32 + i * 8;
    gl_lds16(A + (size_t)(m0 + r + srow) * K + sseg, &As[0][r][0]);
    gl_lds16(W + (size_t)(n0 + r + srow) * K + sseg, &Bs[0][r][0]);
  }
  asm volatile("s_waitcnt vmcnt(0)" ::: "memory");
  __builtin_amdgcn_s_barrier();
#pragma unroll
  for (int i = 0; i < 4; i++) {
    int r = w * 32 + i * 8;
    gl_lds16(A + (size_t)(m0 + r + srow) * K + 64 + sseg, &As[1][r][0]);
    gl_lds16(W + (size_t)(n0 + r + srow) * K + 64 + sseg, &Bs[1][r][0]);
  }

  for (int s = 0; s < nsteps; s++) {
    const int p = s & 1;
    asm volatile("" ::: "memory");     // pin LDS reads below the last barrier

#pragma unroll
    for (int h = 0; h < 2; h++) {
      bf16x8 xf[4], wf[4];
#pragma unroll
      for (int j = 0; j < 4; j++)
        xf[j] = *(const bf16x8*)&As[p][wr + j * 16 + c][((h * 4 + g) ^ (c & 7)) * 8];
#pragma unroll
      for (int i = 0; i < 4; i++)
        wf[i] = *(const bf16x8*)&Bs[p][wc + i * 16 + c][((h * 4 + g) ^ (c & 7)) * 8];
#pragma unroll
      for (int i = 0; i < 4; i++)
#pragma unroll
        for (int j = 0; j < 4; j++)
          acc[i][j] = __builtin_amdgcn_mfma_f32_16x16x32_bf16(wf[i], xf[j],
                                                              acc[i][j], 0, 0, 0);
    }

    if (s + 1 < nsteps) {
      asm volatile("" ::: "memory");
      __builtin_amdgcn_s_barrier();    // B1: all waves done reading buf p
      asm volatile("" ::: "memory");
      if (s + 2 < nsteps) {
        const int k0 = (s + 2) << 6;
#pragma unroll
        for (int i = 0; i < 4; i++) {
          int r = w * 32 + i * 8;
          gl_lds16(A + (size_t)(m0 + r + srow) * K + k0 + sseg, &As[p][r][0]);
          gl_lds16(W + (size_t)(n0 + r + srow) * K + k0 + sseg, &Bs[p][r][0]);
        }
        asm volatile("s_waitcnt vmcnt(8)" ::: "memory");  // own t+1 landed
      } else {
        asm volatile("s_waitcnt vmcnt(0)" ::: "memory");  // tail drain
      }
      __builtin_amdgcn_s_barrier();    // B2: every wave's t+1 loads landed
    }
  }

  // epilogue: D^T tile — row = o (4 consecutive per thread), col = m (lane c)
#pragma unroll
  for (int i = 0; i < 4; i++) {
    const int ob = n0 + wc + i * 16 + g * 4;     // o base, +r consecutive
    const f32x4 bv = *(const f32x4*)&bias[ob];   // 16B-aligned
    int which = 0, hh = 0, d0 = 0;
    if (MODE == 0) {
      which = ob / EMBED;
      int rem = ob - which * EMBED;
      hh = rem >> 6;
      d0 = rem & 63;
    }
#pragma unroll
    for (int j = 0; j < 4; j++) {
      const int m = m0 + wr + j * 16 + c;
      f32x4 v = acc[i][j] + bv;
      if (MODE == 0) {
        const int bb = m >> 11, n = m & 2047;
        const size_t bh = (size_t)bb * NHEAD + hh;
        if (which == 0) {
          s16x4 q4;
#pragma unroll
          for (int r = 0; r < 4; r++)
            q4[r] = (short)__bfloat16_as_ushort(f2b(v[r] * 0.1803368801f));
          *(s16x4*)&outQ[(bh * SEQ + n) * HDIM + d0] = q4;
        } else if (which == 1) {
          s16x4 k4;
#pragma unroll
          for (int r = 0; r < 4; r++)
            k4[r] = (short)__bfloat16_as_ushort(f2b(v[r]));
          *(s16x4*)&outK[(bh * SEQ + n) * HDIM + d0] = k4;
        } else {
#pragma unroll
          for (int r = 0; r < 4; r++)
            outV[(bh * HDIM + d0 + r) * SEQ + n] = f2b(v[r]);
        }
      } else {
        *(f32x4*)&outF[(size_t)m * N + ob] = v;
      }
    }
  }
}

// ---------------------------------------------------------------------------
// Flash MFMA attention v7 — measured-best structure (82.3-83.4 µs), FROZEN.
// R14 post-mortem: v8 (dbuf + single barrier + setprio) was NULL-to-negative
// (84.7 µs) — attn is not barrier/drain-bound; plateau is structural
// (LDS traffic + 3 waves/SIMD latency hiding).
//   S^T = K . Q^T ; O^T = V^T . P^T  (fragment maps verified R3-R12)
// Block = 128 q-rows, 4 waves x 2 groups of 16. LDS 34.8 KB; grid 768 = 3/CU.
// Per iter: S(ks) -> B1 -> DMA K(jt+1) -> softmax/Pt/PV(vs) -> B2 -> DMA V(jt+1).
// ---------------------------------------------------------------------------
__global__ __launch_bounds__(256, 4) void attn_mfma(
    const bf16* __restrict__ Q, const bf16* __restrict__ Kk,
    const bf16* __restrict__ V, bf16* __restrict__ O) {
  __shared__ bf16 Ks[64 * 64];
  __shared__ bf16 Vts[64 * 64];
  __shared__ bf16 Pt[8][16 * 72];

  const int blk = blockIdx.x;
  const int bh = blk >> 4;               // 16 q-tiles (of 128) per (b,h)
  const int qt = blk & 15;
  const int bb = bh / NHEAD;
  const int h = bh % NHEAD;
  const int t = threadIdx.x;
  const int lane = t & 63;
  const int w = t >> 6;
  const int g = lane >> 4;
  const int c = lane & 15;
  const size_t base = (size_t)bh * SEQ * HDIM;
  const int mb0 = qt * 128 + w * 16;     // q-group 0 rows
  const int mb1 = mb0 + 64;              // q-group 1 rows

  // DMA lane mapping (XOR chunk swizzle for K/V, verified R5-R12)
  const int r8 = lane >> 3;
  const int l8 = lane & 7;
  const int gch = l8 ^ (r8 & 7);
  const int q0 = w * 2, q1 = w * 2 + 1;

  // Q fragments (B operand), one pair per q-group
  bf16x8 qa[2][2];
#pragma unroll
  for (int kh = 0; kh < 2; kh++) {
    qa[0][kh] = *(const bf16x8*)(Q + base + (size_t)(mb0 + c) * HDIM + kh * 32 + g * 8);
    qa[1][kh] = *(const bf16x8*)(Q + base + (size_t)(mb1 + c) * HDIM + kh * 32 + g * 8);
  }

  // all-ones A fragment for the l-row-sum MFMA
  bf16x8 ones;
#pragma unroll
  for (int i = 0; i < 8; i++) ones[i] = (short)0x3F80;

  f32x4 o[2][4] = {};
  f32x4 o_l[2] = {};

  // prologue: DMA tile 0 (K and V), drain before first use
  gl_lds16(Kk + base + (size_t)(q0 * 8 + r8) * HDIM + gch * 8, &Ks[q0 * 8 * 64]);
  gl_lds16(Kk + base + (size_t)(q1 * 8 + r8) * HDIM + gch * 8, &Ks[q1 * 8 * 64]);
  gl_lds16(V + base + (size_t)(q0 * 8 + r8) * SEQ + gch * 8, &Vts[q0 * 8 * 64]);
  gl_lds16(V + base + (size_t)(q1 * 8 + r8) * SEQ + gch * 8, &Vts[q1 * 8 * 64]);
  __syncthreads();

  bf16* const Pt0 = Pt[w * 2];
  bf16* const Pt1 = Pt[w * 2 + 1];

  for (int jt = 0; jt < SEQ / 64; jt++) {
    // S^T = K . Q^T — each kb read feeds both q-groups
    f32x4 s[2][4] = {};
#pragma unroll
    for (int nt = 0; nt < 4; nt++) {
#pragma unroll
      for (int kh = 0; kh < 2; kh++) {
        bf16x8 kb = *(const bf16x8*)&Ks[(nt * 16 + c) * 64 + ((kh * 4 + g) ^ (c & 7)) * 8];
        s[0][nt] = __builtin_amdgcn_mfma_f32_16x16x32_bf16(kb, qa[0][kh], s[0][nt], 0, 0, 0);
        s[1][nt] = __builtin_amdgcn_mfma_f32_16x16x32_bf16(kb, qa[1][kh], s[1][nt], 0, 0, 0);
      }
    }

    __syncthreads();  // B1: all waves done reading Ks; drains V(jt) DMA
    if (jt + 1 < SEQ / 64) {  // DMA K(jt+1); softmax+PV time to land
      const int jb = (jt + 1) * 64;
      gl_lds16(Kk + base + (size_t)(jb + q0 * 8 + r8) * HDIM + gch * 8, &Ks[q0 * 8 * 64]);
      gl_lds16(Kk + base + (size_t)(jb + q1 * 8 + r8) * HDIM + gch * 8, &Ks[q1 * 8 * 64]);
    }

    // p = exp2(s); pack 4 consecutive j; plain stride-72 Pt, per group
#pragma unroll
    for (int nt = 0; nt < 4; nt++) {
      float a0 = __builtin_amdgcn_exp2f(s[0][nt][0]);
      float a1 = __builtin_amdgcn_exp2f(s[0][nt][1]);
      float a2 = __builtin_amdgcn_exp2f(s[0][nt][2]);
      float a3 = __builtin_amdgcn_exp2f(s[0][nt][3]);
      u32x2 pw0 = {pk2(a0, a1), pk2(a2, a3)};
      *(u32x2*)&Pt0[c * 72 + nt * 16 + g * 4] = pw0;
      float b0 = __builtin_amdgcn_exp2f(s[1][nt][0]);
      float b1 = __builtin_amdgcn_exp2f(s[1][nt][1]);
      float b2 = __builtin_amdgcn_exp2f(s[1][nt][2]);
      float b3 = __builtin_amdgcn_exp2f(s[1][nt][3]);
      u32x2 pw1 = {pk2(b0, b1), pk2(b2, b3)};
      *(u32x2*)&Pt1[c * 72 + nt * 16 + g * 4] = pw1;
    }
    bf16x8 pb[2][2];
    pb[0][0] = *(const bf16x8*)&Pt0[c * 72 + g * 8];
    pb[0][1] = *(const bf16x8*)&Pt0[c * 72 + 32 + g * 8];
    pb[1][0] = *(const bf16x8*)&Pt1[c * 72 + g * 8];
    pb[1][1] = *(const bf16x8*)&Pt1[c * 72 + 32 + g * 8];

    // O^T += V^T . P^T — each vb read feeds both q-groups;
    // l += ones . P^T in the MFMA pipe
#pragma unroll
    for (int dt = 0; dt < 4; dt++) {
      bf16x8 vb0 = *(const bf16x8*)&Vts[(dt * 16 + c) * 64 + ((0 + g) ^ (c & 7)) * 8];
      bf16x8 vb1 = *(const bf16x8*)&Vts[(dt * 16 + c) * 64 + ((4 + g) ^ (c & 7)) * 8];
      o[0][dt] = __builtin_amdgcn_mfma_f32_16x16x32_bf16(vb0, pb[0][0], o[0][dt], 0, 0, 0);
      o[0][dt] = __builtin_amdgcn_mfma_f32_16x16x32_bf16(vb1, pb[0][1], o[0][dt], 0, 0, 0);
      o[1][dt] = __builtin_amdgcn_mfma_f32_16x16x32_bf16(vb0, pb[1][0], o[1][dt], 0, 0, 0);
      o[1][dt] = __builtin_amdgcn_mfma_f32_16x16x32_bf16(vb1, pb[1][1], o[1][dt], 0, 0, 0);
    }
    o_l[0] = __builtin_amdgcn_mfma_f32_16x16x32_bf16(ones, pb[0][0], o_l[0], 0, 0, 0);
    o_l[0] = __builtin_amdgcn_mfma_f32_16x16x32_bf16(ones, pb[0][1], o_l[0], 0, 0, 0);
    o_l[1] = __builtin_amdgcn_mfma_f32_16x16x32_bf16(ones, pb[1][0], o_l[1], 0, 0, 0);
    o_l[1] = __builtin_amdgcn_mfma_f32_16x16x32_bf16(ones, pb[1][1], o_l[1], 0, 0, 0);

    __syncthreads();  // B2: all waves done reading Vts; drains K(jt+1) DMA
    if (jt + 1 < SEQ / 64) {  // DMA V(jt+1); S-phase time to land
      const int jb = (jt + 1) * 64;
      gl_lds16(V + base + (size_t)(q0 * 8 + r8) * SEQ + jb + gch * 8, &Vts[q0 * 8 * 64]);
      gl_lds16(V + base + (size_t)(q1 * 8 + r8) * SEQ + jb + gch * 8, &Vts[q1 * 8 * 64]);
    }
  }

  // epilogue: l[c] replicated in every o_l reg — no shuffles; packed stores
#pragma unroll
  for (int grp = 0; grp < 2; grp++) {
    const float inv = __builtin_amdgcn_rcpf(o_l[grp][0]);
    const int mb = grp ? mb1 : mb0;
    const size_t rowoff = ((size_t)bb * SEQ + mb + c) * EMBED + h * 64 + g * 4;
#pragma unroll
    for (int dt = 0; dt < 4; dt++) {
      s16x4 ov;
#pragma unroll
      for (int r = 0; r < 4; r++)
        ov[r] = (short)__bfloat16_as_ushort(f2b(o[grp][dt][r] * inv));
      *(s16x4*)&O[rowoff + dt * 16] = ov;
    }
  }
}

// ---------------------------------------------------------------------------
extern "C" void kernel_launch(void* const* d_in, const int* in_sizes, int n_in,
                              void* d_out, int out_size, void* d_ws,
                              size_t ws_size, hipStream_t stream) {
  const float* x      = (const float*)d_in[0];
  const float* w_qkv  = (const float*)d_in[1];
  const float* b_qkv  = (const float*)d_in[2];
  const float* w_proj = (const float*)d_in[3];
  const float* b_proj = (const float*)d_in[4];

  const size_t per = (size_t)BATCH * NHEAD * SEQ * HDIM;
  bf16* Qp = (bf16*)d_ws;
  bf16* Kp = Qp + per;
  bf16* Vp = Kp + per;                 // [B,H,D,N]
  bf16* xb = Vp + per;                 // x bf16; reused as AO after QKV GEMM
  bf16* wqkvb = xb + per;
  bf16* wprojb = wqkvb + (size_t)3 * EMBED * EMBED;
  bf16* AO = xb;

  const int ncvt = NX4 + NWQ4 + NWP4;  // f32x4 groups total
  cvt_all<<<dim3((ncvt + 255) / 256), 256, 0, stream>>>(x, w_qkv, w_proj, xb,
                                                        wqkvb, wprojb);

  dim3 g1(2304 / 128, 8192 / 128);
  gemm_mfma<0><<<g1, 256, 0, stream>>>(xb, wqkvb, b_qkv, nullptr, Qp, Kp, Vp,
                                       BATCH * SEQ, 3 * EMBED, EMBED);

  // 128 q-rows per block: B*H*(SEQ/128) = 768 blocks, 34.8 KB LDS
  attn_mfma<<<dim3(BATCH * NHEAD * (SEQ / 128)), 256, 0, stream>>>(Qp, Kp, Vp, AO);

  dim3 g2(768 / 128, 8192 / 128);
  gemm_mfma<1><<<g2, 256, 0, stream>>>(AO, wprojb, b_proj, (float*)d_out,
                                       nullptr, nullptr, nullptr, BATCH * SEQ,
                                       EMBED, EMBED);
}

// Round 5
// 220.621 us; speedup vs baseline: 1.0372x; 1.0372x over previous
//
#include <hip/hip_runtime.h>
#include <hip/hip_bf16.h>
#include <math.h>

#define EMBED 768
#define NHEAD 12
#define HDIM 64
#define SEQ 2048
#define BATCH 4

typedef __hip_bfloat16 bf16;
typedef __attribute__((ext_vector_type(8))) short bf16x8;   // 8 bf16 / 4 VGPRs
typedef __attribute__((ext_vector_type(4))) short s16x4;
typedef __attribute__((ext_vector_type(4))) float f32x4;
typedef __attribute__((ext_vector_type(2))) unsigned int u32x2;

__device__ inline float b2f(bf16 v) { return __bfloat162float(v); }
__device__ inline bf16 f2b(float v) { return __float2bfloat16(v); }
__device__ inline unsigned pk2(float a, float b) {
  return (unsigned)__bfloat16_as_ushort(f2b(a)) |
         ((unsigned)__bfloat16_as_ushort(f2b(b)) << 16);
}

// async global->LDS, 16B per lane. LDS dest = wave-uniform base + lane*16.
__device__ inline void gl_lds16(const bf16* g, bf16* l) {
  __builtin_amdgcn_global_load_lds(
      (const __attribute__((address_space(1))) void*)g,
      (__attribute__((address_space(3))) void*)l, 16, 0, 0);
}

#define NX4  (BATCH * SEQ * EMBED / 4)
#define NWQ4 (3 * EMBED * EMBED / 4)
#define NWP4 (EMBED * EMBED / 4)

// ---------------------------------------------------------------------------
// One fused f32->bf16 convert for x, w_qkv, w_proj (segmented index space).
// ---------------------------------------------------------------------------
__global__ __launch_bounds__(256) void cvt_all(
    const float* __restrict__ x, const float* __restrict__ wq,
    const float* __restrict__ wp, bf16* __restrict__ xb,
    bf16* __restrict__ wqb, bf16* __restrict__ wpb) {
  int i = blockIdx.x * 256 + threadIdx.x;
  const float* src;
  bf16* dst;
  int k;
  if (i < NX4) {
    src = x; dst = xb; k = i;
  } else if (i < NX4 + NWQ4) {
    src = wq; dst = wqb; k = i - NX4;
  } else if (i < NX4 + NWQ4 + NWP4) {
    src = wp; dst = wpb; k = i - NX4 - NWQ4;
  } else {
    return;
  }
  float4 v = ((const float4*)src)[k];
  s16x4 o;
  o[0] = (short)__bfloat16_as_ushort(f2b(v.x));
  o[1] = (short)__bfloat16_as_ushort(f2b(v.y));
  o[2] = (short)__bfloat16_as_ushort(f2b(v.z));
  o[3] = (short)__bfloat16_as_ushort(f2b(v.w));
  *(s16x4*)(dst + 4 * (size_t)k) = o;
}

// ---------------------------------------------------------------------------
// MFMA GEMM, operand-swapped (computes C^T tiles).
// R17: back to the EXACT R2-verified loop (single-buffer BK=64, both-sides
//   XOR swizzle, 2 __syncthreads/step — measured best 222.8 µs total).
//   R3/R4 post-mortems: within-block pipelining (dbuf, depth-2 counted
//   vmcnt, XCD swizzle) all null-to-negative; the operative mechanism is
//   CROSS-BLOCK wave overlap => maximize resident blocks/CU.
//   + __launch_bounds__(256,4): cap VGPR <=128 so occupancy is 4 blocks/CU
//     (m69 steps: vgpr in (128,256] would give only 2). LDS 32KB*4=128<=160.
//   + template<TM>: gemm1 (M=8192,N=768) was grid-starved at 128^2 tiles
//     (384 blocks = 1.5/CU). TM=64 doubles its grid to 768 blocks.
// R14 (kept): BK=64, both-sides XOR swizzle — DMA source chunk
//   (lane&7)^(lane>>3), read slot (h*4+g)^(c&7); slot^row cancels, register
//   fragment contents identical to the BK=32 layout (verified R2).
// MODE 0: scatter Q(x 0.125*log2e) -> [B,H,N,D], K -> [B,H,N,D],
//         V -> [B,H,D,N] (bf16)
// MODE 1: outF[m,o] f32 row-major
// ---------------------------------------------------------------------------
template <int MODE, int TM>
__global__ __launch_bounds__(256, 4) void gemm_mfma(
    const bf16* __restrict__ A, const bf16* __restrict__ W,
    const float* __restrict__ bias, float* __restrict__ outF,
    bf16* __restrict__ outQ, bf16* __restrict__ outK, bf16* __restrict__ outV,
    int M, int N, int K) {
  __shared__ bf16 As[TM][64];
  __shared__ bf16 Bs[128][64];
  const int t = threadIdx.x;
  const int w = t >> 6;
  const int lane = t & 63;
  const int g = lane >> 4, c = lane & 15;
  const int m0 = blockIdx.y * TM, n0 = blockIdx.x * 128;
  constexpr int MJ = TM / 32;          // m-frags per wave: 4 (TM=128) / 2 (64)
  const int wr = (w >> 1) * (TM / 2);  // m-dim tile base (As)
  const int wc = (w & 1) * 64;         // o-dim tile base (Bs)

  // DMA mapping: 1KB per instr = 8 rows x 128B. Source chunk pre-swizzled.
  const int srow = lane >> 3;          // 0..7 row within 8-row stripe
  const int l8 = lane & 7;             // LDS 16B-slot within row
  const int sseg = (l8 ^ srow) * 8;    // swizzled global chunk (bf16 elems)

  f32x4 acc[4][MJ] = {};  // acc[i][j]: i over o-tiles (W), j over m-tiles (x)

  for (int k0 = 0; k0 < K; k0 += 64) {
#pragma unroll
    for (int i = 0; i < 4; i++) {
      int r = w * 32 + i * 8;
      gl_lds16(W + (size_t)(n0 + r + srow) * K + k0 + sseg, &Bs[r][0]);
    }
#pragma unroll
    for (int i = 0; i < TM / 32; i++) {
      int r = w * (TM / 4) + i * 8;
      gl_lds16(A + (size_t)(m0 + r + srow) * K + k0 + sseg, &As[r][0]);
    }
    __syncthreads();

#pragma unroll
    for (int h = 0; h < 2; h++) {
      bf16x8 xf[MJ], wf[4];
#pragma unroll
      for (int j = 0; j < MJ; j++)
        xf[j] = *(const bf16x8*)&As[wr + j * 16 + c][((h * 4 + g) ^ (c & 7)) * 8];
#pragma unroll
      for (int i = 0; i < 4; i++)
        wf[i] = *(const bf16x8*)&Bs[wc + i * 16 + c][((h * 4 + g) ^ (c & 7)) * 8];
#pragma unroll
      for (int i = 0; i < 4; i++)
#pragma unroll
        for (int j = 0; j < MJ; j++)
          acc[i][j] = __builtin_amdgcn_mfma_f32_16x16x32_bf16(wf[i], xf[j],
                                                              acc[i][j], 0, 0, 0);
    }
    __syncthreads();
  }

  // epilogue: D^T tile — row = o (4 consecutive per thread), col = m (lane c)
#pragma unroll
  for (int i = 0; i < 4; i++) {
    const int ob = n0 + wc + i * 16 + g * 4;     // o base, +r consecutive
    const f32x4 bv = *(const f32x4*)&bias[ob];   // 16B-aligned
    int which = 0, hh = 0, d0 = 0;
    if (MODE == 0) {
      which = ob / EMBED;
      int rem = ob - which * EMBED;
      hh = rem >> 6;
      d0 = rem & 63;
    }
#pragma unroll
    for (int j = 0; j < MJ; j++) {
      const int m = m0 + wr + j * 16 + c;
      f32x4 v = acc[i][j] + bv;
      if (MODE == 0) {
        const int bb = m >> 11, n = m & 2047;
        const size_t bh = (size_t)bb * NHEAD + hh;
        if (which == 0) {
          s16x4 q4;
#pragma unroll
          for (int r = 0; r < 4; r++)
            q4[r] = (short)__bfloat16_as_ushort(f2b(v[r] * 0.1803368801f));
          *(s16x4*)&outQ[(bh * SEQ + n) * HDIM + d0] = q4;
        } else if (which == 1) {
          s16x4 k4;
#pragma unroll
          for (int r = 0; r < 4; r++)
            k4[r] = (short)__bfloat16_as_ushort(f2b(v[r]));
          *(s16x4*)&outK[(bh * SEQ + n) * HDIM + d0] = k4;
        } else {
#pragma unroll
          for (int r = 0; r < 4; r++)
            outV[(bh * HDIM + d0 + r) * SEQ + n] = f2b(v[r]);
        }
      } else {
        *(f32x4*)&outF[(size_t)m * N + ob] = v;
      }
    }
  }
}

// ---------------------------------------------------------------------------
// Flash MFMA attention v7 — measured-best structure (82.3-83.4 µs), FROZEN.
// R14 post-mortem: v8 (dbuf + single barrier + setprio) was NULL-to-negative
// (84.7 µs) — attn is not barrier/drain-bound; plateau is structural
// (LDS traffic + 3 waves/SIMD latency hiding).
//   S^T = K . Q^T ; O^T = V^T . P^T  (fragment maps verified R3-R12)
// Block = 128 q-rows, 4 waves x 2 groups of 16. LDS 34.8 KB; grid 768 = 3/CU.
// Per iter: S(ks) -> B1 -> DMA K(jt+1) -> softmax/Pt/PV(vs) -> B2 -> DMA V(jt+1).
// ---------------------------------------------------------------------------
__global__ __launch_bounds__(256, 4) void attn_mfma(
    const bf16* __restrict__ Q, const bf16* __restrict__ Kk,
    const bf16* __restrict__ V, bf16* __restrict__ O) {
  __shared__ bf16 Ks[64 * 64];
  __shared__ bf16 Vts[64 * 64];
  __shared__ bf16 Pt[8][16 * 72];

  const int blk = blockIdx.x;
  const int bh = blk >> 4;               // 16 q-tiles (of 128) per (b,h)
  const int qt = blk & 15;
  const int bb = bh / NHEAD;
  const int h = bh % NHEAD;
  const int t = threadIdx.x;
  const int lane = t & 63;
  const int w = t >> 6;
  const int g = lane >> 4;
  const int c = lane & 15;
  const size_t base = (size_t)bh * SEQ * HDIM;
  const int mb0 = qt * 128 + w * 16;     // q-group 0 rows
  const int mb1 = mb0 + 64;              // q-group 1 rows

  // DMA lane mapping (XOR chunk swizzle for K/V, verified R5-R12)
  const int r8 = lane >> 3;
  const int l8 = lane & 7;
  const int gch = l8 ^ (r8 & 7);
  const int q0 = w * 2, q1 = w * 2 + 1;

  // Q fragments (B operand), one pair per q-group
  bf16x8 qa[2][2];
#pragma unroll
  for (int kh = 0; kh < 2; kh++) {
    qa[0][kh] = *(const bf16x8*)(Q + base + (size_t)(mb0 + c) * HDIM + kh * 32 + g * 8);
    qa[1][kh] = *(const bf16x8*)(Q + base + (size_t)(mb1 + c) * HDIM + kh * 32 + g * 8);
  }

  // all-ones A fragment for the l-row-sum MFMA
  bf16x8 ones;
#pragma unroll
  for (int i = 0; i < 8; i++) ones[i] = (short)0x3F80;

  f32x4 o[2][4] = {};
  f32x4 o_l[2] = {};

  // prologue: DMA tile 0 (K and V), drain before first use
  gl_lds16(Kk + base + (size_t)(q0 * 8 + r8) * HDIM + gch * 8, &Ks[q0 * 8 * 64]);
  gl_lds16(Kk + base + (size_t)(q1 * 8 + r8) * HDIM + gch * 8, &Ks[q1 * 8 * 64]);
  gl_lds16(V + base + (size_t)(q0 * 8 + r8) * SEQ + gch * 8, &Vts[q0 * 8 * 64]);
  gl_lds16(V + base + (size_t)(q1 * 8 + r8) * SEQ + gch * 8, &Vts[q1 * 8 * 64]);
  __syncthreads();

  bf16* const Pt0 = Pt[w * 2];
  bf16* const Pt1 = Pt[w * 2 + 1];

  for (int jt = 0; jt < SEQ / 64; jt++) {
    // S^T = K . Q^T — each kb read feeds both q-groups
    f32x4 s[2][4] = {};
#pragma unroll
    for (int nt = 0; nt < 4; nt++) {
#pragma unroll
      for (int kh = 0; kh < 2; kh++) {
        bf16x8 kb = *(const bf16x8*)&Ks[(nt * 16 + c) * 64 + ((kh * 4 + g) ^ (c & 7)) * 8];
        s[0][nt] = __builtin_amdgcn_mfma_f32_16x16x32_bf16(kb, qa[0][kh], s[0][nt], 0, 0, 0);
        s[1][nt] = __builtin_amdgcn_mfma_f32_16x16x32_bf16(kb, qa[1][kh], s[1][nt], 0, 0, 0);
      }
    }

    __syncthreads();  // B1: all waves done reading Ks; drains V(jt) DMA
    if (jt + 1 < SEQ / 64) {  // DMA K(jt+1); softmax+PV time to land
      const int jb = (jt + 1) * 64;
      gl_lds16(Kk + base + (size_t)(jb + q0 * 8 + r8) * HDIM + gch * 8, &Ks[q0 * 8 * 64]);
      gl_lds16(Kk + base + (size_t)(jb + q1 * 8 + r8) * HDIM + gch * 8, &Ks[q1 * 8 * 64]);
    }

    // p = exp2(s); pack 4 consecutive j; plain stride-72 Pt, per group
#pragma unroll
    for (int nt = 0; nt < 4; nt++) {
      float a0 = __builtin_amdgcn_exp2f(s[0][nt][0]);
      float a1 = __builtin_amdgcn_exp2f(s[0][nt][1]);
      float a2 = __builtin_amdgcn_exp2f(s[0][nt][2]);
      float a3 = __builtin_amdgcn_exp2f(s[0][nt][3]);
      u32x2 pw0 = {pk2(a0, a1), pk2(a2, a3)};
      *(u32x2*)&Pt0[c * 72 + nt * 16 + g * 4] = pw0;
      float b0 = __builtin_amdgcn_exp2f(s[1][nt][0]);
      float b1 = __builtin_amdgcn_exp2f(s[1][nt][1]);
      float b2 = __builtin_amdgcn_exp2f(s[1][nt][2]);
      float b3 = __builtin_amdgcn_exp2f(s[1][nt][3]);
      u32x2 pw1 = {pk2(b0, b1), pk2(b2, b3)};
      *(u32x2*)&Pt1[c * 72 + nt * 16 + g * 4] = pw1;
    }
    bf16x8 pb[2][2];
    pb[0][0] = *(const bf16x8*)&Pt0[c * 72 + g * 8];
    pb[0][1] = *(const bf16x8*)&Pt0[c * 72 + 32 + g * 8];
    pb[1][0] = *(const bf16x8*)&Pt1[c * 72 + g * 8];
    pb[1][1] = *(const bf16x8*)&Pt1[c * 72 + 32 + g * 8];

    // O^T += V^T . P^T — each vb read feeds both q-groups;
    // l += ones . P^T in the MFMA pipe
#pragma unroll
    for (int dt = 0; dt < 4; dt++) {
      bf16x8 vb0 = *(const bf16x8*)&Vts[(dt * 16 + c) * 64 + ((0 + g) ^ (c & 7)) * 8];
      bf16x8 vb1 = *(const bf16x8*)&Vts[(dt * 16 + c) * 64 + ((4 + g) ^ (c & 7)) * 8];
      o[0][dt] = __builtin_amdgcn_mfma_f32_16x16x32_bf16(vb0, pb[0][0], o[0][dt], 0, 0, 0);
      o[0][dt] = __builtin_amdgcn_mfma_f32_16x16x32_bf16(vb1, pb[0][1], o[0][dt], 0, 0, 0);
      o[1][dt] = __builtin_amdgcn_mfma_f32_16x16x32_bf16(vb0, pb[1][0], o[1][dt], 0, 0, 0);
      o[1][dt] = __builtin_amdgcn_mfma_f32_16x16x32_bf16(vb1, pb[1][1], o[1][dt], 0, 0, 0);
    }
    o_l[0] = __builtin_amdgcn_mfma_f32_16x16x32_bf16(ones, pb[0][0], o_l[0], 0, 0, 0);
    o_l[0] = __builtin_amdgcn_mfma_f32_16x16x32_bf16(ones, pb[0][1], o_l[0], 0, 0, 0);
    o_l[1] = __builtin_amdgcn_mfma_f32_16x16x32_bf16(ones, pb[1][0], o_l[1], 0, 0, 0);
    o_l[1] = __builtin_amdgcn_mfma_f32_16x16x32_bf16(ones, pb[1][1], o_l[1], 0, 0, 0);

    __syncthreads();  // B2: all waves done reading Vts; drains K(jt+1) DMA
    if (jt + 1 < SEQ / 64) {  // DMA V(jt+1); S-phase time to land
      const int jb = (jt + 1) * 64;
      gl_lds16(V + base + (size_t)(q0 * 8 + r8) * SEQ + jb + gch * 8, &Vts[q0 * 8 * 64]);
      gl_lds16(V + base + (size_t)(q1 * 8 + r8) * SEQ + jb + gch * 8, &Vts[q1 * 8 * 64]);
    }
  }

  // epilogue: l[c] replicated in every o_l reg — no shuffles; packed stores
#pragma unroll
  for (int grp = 0; grp < 2; grp++) {
    const float inv = __builtin_amdgcn_rcpf(o_l[grp][0]);
    const int mb = grp ? mb1 : mb0;
    const size_t rowoff = ((size_t)bb * SEQ + mb + c) * EMBED + h * 64 + g * 4;
#pragma unroll
    for (int dt = 0; dt < 4; dt++) {
      s16x4 ov;
#pragma unroll
      for (int r = 0; r < 4; r++)
        ov[r] = (short)__bfloat16_as_ushort(f2b(o[grp][dt][r] * inv));
      *(s16x4*)&O[rowoff + dt * 16] = ov;
    }
  }
}

// ---------------------------------------------------------------------------
extern "C" void kernel_launch(void* const* d_in, const int* in_sizes, int n_in,
                              void* d_out, int out_size, void* d_ws,
                              size_t ws_size, hipStream_t stream) {
  const float* x      = (const float*)d_in[0];
  const float* w_qkv  = (const float*)d_in[1];
  const float* b_qkv  = (const float*)d_in[2];
  const float* w_proj = (const float*)d_in[3];
  const float* b_proj = (const float*)d_in[4];

  const size_t per = (size_t)BATCH * NHEAD * SEQ * HDIM;
  bf16* Qp = (bf16*)d_ws;
  bf16* Kp = Qp + per;
  bf16* Vp = Kp + per;                 // [B,H,D,N]
  bf16* xb = Vp + per;                 // x bf16; reused as AO after QKV GEMM
  bf16* wqkvb = xb + per;
  bf16* wprojb = wqkvb + (size_t)3 * EMBED * EMBED;
  bf16* AO = xb;

  const int ncvt = NX4 + NWQ4 + NWP4;  // f32x4 groups total
  cvt_all<<<dim3((ncvt + 255) / 256), 256, 0, stream>>>(x, w_qkv, w_proj, xb,
                                                        wqkvb, wprojb);

  dim3 g1(2304 / 128, 8192 / 128);
  gemm_mfma<0, 128><<<g1, 256, 0, stream>>>(xb, wqkvb, b_qkv, nullptr, Qp, Kp,
                                            Vp, BATCH * SEQ, 3 * EMBED, EMBED);

  // 128 q-rows per block: B*H*(SEQ/128) = 768 blocks, 34.8 KB LDS
  attn_mfma<<<dim3(BATCH * NHEAD * (SEQ / 128)), 256, 0, stream>>>(Qp, Kp, Vp, AO);

  // proj GEMM: TM=64 -> grid (6,128)=768 blocks (was 384 = grid-starved)
  dim3 g2(768 / 128, 8192 / 64);
  gemm_mfma<1, 64><<<g2, 256, 0, stream>>>(AO, wprojb, b_proj, (float*)d_out,
                                           nullptr, nullptr, nullptr,
                                           BATCH * SEQ, EMBED, EMBED);
}